// Round 3
// baseline (45126.501 us; speedup 1.0000x reference)
//
#include <hip/hip_runtime.h>
#include <cstdint>

// RoleConditionedLSTMDecoder on MI355X (gfx950) — R3: row-owner persistent kernel.
// B=1024 P=22 N=22528 H=512 4H=2048 T=100. Rows are independent across the
// sequence -> 256 blocks (1/CU, 512 thr = 8 waves) each own 88 rows (padded 96)
// and run all 100 steps with NO cross-block sync. Weights read from L2 each step.
// One-barrier/kt double-buffered LDS pipeline (BK=32); static LDS 50 KB (<64 KB).
// Gate-permuted cols: j = tile*128 + half*64 + gate*16 + c16; h-col = tile*32+half*16+c16.

#define DEVI __device__ __forceinline__

typedef __bf16 bf16x8 __attribute__((ext_vector_type(8)));
typedef float  f32x4  __attribute__((ext_vector_type(4)));

static constexpr int NR_REAL = 22528;    // B*P
static constexpr int RPB     = 88;       // real rows per block
static constexpr int RPB_PAD = 96;       // padded rows per block (6 M16 tiles)
static constexpr int NBLK    = 256;
static constexpr int NP      = NBLK * RPB_PAD;   // 24576 padded rows
static constexpr int T_STEPS = 100;

DEVI unsigned short f2bf(float f) {
  unsigned u = __float_as_uint(f);
  u = u + 0x7FFFu + ((u >> 16) & 1u);   // RNE
  return (unsigned short)(u >> 16);
}
DEVI float bf2f(unsigned short h) { return __uint_as_float(((unsigned)h) << 16); }

DEVI float fast_sigmoid(float x) {
  float e = __builtin_amdgcn_exp2f(-1.442695041f * x);
  return __builtin_amdgcn_rcpf(1.0f + e);
}
DEVI float fast_tanh(float x) {
  float e = __builtin_amdgcn_exp2f(2.885390082f * x);   // e^(2x)
  return 1.0f - 2.0f * __builtin_amdgcn_rcpf(e + 1.0f);
}

DEVI void async_copy16(const void* g, void* l) {
  __builtin_amdgcn_global_load_lds(
      (const __attribute__((address_space(1))) void*)g,
      (__attribute__((address_space(3))) void*)l, 16, 0, 0);
}

// ---------------- R2 gemm_core (used only by one-shot k_static) ----------------
template <int KITERS, int KSWITCH>
DEVI void gemm_core(const unsigned short* __restrict__ A1, int lda1,
                    const unsigned short* __restrict__ A2, int lda2,
                    const unsigned short* __restrict__ B1, int ldb1,
                    const unsigned short* __restrict__ B2, int ldb2,
                    unsigned short* lds, f32x4 acc[4][4], int tid) {
  const int lane = tid & 63, wid = tid >> 6;
  const int wm = wid & 1, wn = wid >> 1;
  const int c16 = lane & 15, q = lane >> 4;
#pragma unroll
  for (int i = 0; i < 4; ++i)
#pragma unroll
    for (int j = 0; j < 4; ++j) acc[i][j] = f32x4{0.f, 0.f, 0.f, 0.f};
  for (int kt = 0; kt < KITERS; ++kt) {
    const bool sec = (kt >= KSWITCH);
    const unsigned short* Ab = sec ? A2 : A1;
    const unsigned short* Bb = sec ? B2 : B1;
    const int lda = sec ? lda2 : lda1;
    const int ldb = sec ? ldb2 : ldb1;
    const int kk = (sec ? (kt - KSWITCH) : kt) * 64;
    __syncthreads();
#pragma unroll
    for (int rd = 0; rd < 4; ++rd) {
      int p = rd * 256 + tid;
      int row = p >> 3, u = p & 7, ch = u ^ (row & 7);
      async_copy16(Ab + row * lda + kk + ch * 8, lds + p * 8);
      async_copy16(Bb + row * ldb + kk + ch * 8, lds + 8192 + p * 8);
    }
    __syncthreads();
#pragma unroll
    for (int s = 0; s < 2; ++s) {
      bf16x8 a[4], b[4];
#pragma unroll
      for (int mf = 0; mf < 4; ++mf) {
        int row = wm * 64 + mf * 16 + c16;
        int slot = row * 8 + ((s * 4 + q) ^ (row & 7));
        a[mf] = *(const bf16x8*)(lds + slot * 8);
      }
#pragma unroll
      for (int nf = 0; nf < 4; ++nf) {
        int row = wn * 64 + nf * 16 + c16;
        int slot = row * 8 + ((s * 4 + q) ^ (row & 7));
        b[nf] = *(const bf16x8*)(lds + 8192 + slot * 8);
      }
#pragma unroll
      for (int mf = 0; mf < 4; ++mf)
#pragma unroll
        for (int nf = 0; nf < 4; ++nf)
          acc[mf][nf] = __builtin_amdgcn_mfma_f32_16x16x32_bf16(a[mf], b[nf], acc[mf][nf], 0, 0, 0);
    }
  }
}

// ---------------- prep ----------------
DEVI int orig_row(int j) {
  int tile = j >> 7, rem = j & 127;
  int half = rem >> 6, g = (rem >> 4) & 3, cc = rem & 15;
  return g * 512 + (tile * 32 + half * 16 + cc);
}

__global__ void k_prep_w(const float* __restrict__ Whh0, const float* __restrict__ Wih1,
                         const float* __restrict__ Whh1, const float* __restrict__ Wih0,
                         const float* __restrict__ Wfc1, const float* __restrict__ b0,
                         const float* __restrict__ b1,
                         unsigned short* __restrict__ W0p, unsigned short* __restrict__ Wc1p,
                         unsigned short* __restrict__ Wsp, unsigned short* __restrict__ Wfc1b,
                         float* __restrict__ Wposp, float* __restrict__ b0p, float* __restrict__ b1p) {
  int j = blockIdx.x;       // 0..2047
  int k = threadIdx.x;      // 0..511
  int o = orig_row(j);
  W0p[j * 512 + k]         = f2bf(Whh0[o * 512 + k]);
  Wc1p[j * 1024 + k]       = f2bf(Wih1[o * 512 + k]);
  Wc1p[j * 1024 + 512 + k] = f2bf(Whh1[o * 512 + k]);
  if (k < 384) Wsp[j * 384 + k] = (k < 322) ? f2bf(Wih0[o * 324 + 2 + k]) : (unsigned short)0;
  if (k == 0) {
    Wposp[j * 2 + 0] = Wih0[o * 324 + 0];
    Wposp[j * 2 + 1] = Wih0[o * 324 + 1];
    b0p[j] = b0[o];
    b1p[j] = b1[o];
  }
  if (j < 256) Wfc1b[j * 512 + k] = f2bf(Wfc1[j * 512 + k]);
}

__global__ void k_init_xs(const float* __restrict__ ball, const float* __restrict__ ctx,
                          const int* __restrict__ roles, const float* __restrict__ role_table,
                          unsigned short* __restrict__ Xs) {
  int n = blockIdx.x, col = threadIdx.x;  // padded n in [0, NP)
  int blk = n / RPB_PAD, r = n - blk * RPB_PAD;
  float v = 0.f;
  if (r < RPB && col < 322) {
    int nr = blk * RPB + r;
    int b = nr / 22;
    if (col < 2)        v = ball[b * 2 + col];
    else if (col < 258) v = ctx[(size_t)nr * 256 + col - 2];
    else                v = role_table[roles[nr] * 64 + col - 258];
  }
  Xs[(size_t)n * 384 + col] = f2bf(v);
}

__global__ void k_init_state(const float* __restrict__ pos0, const float* __restrict__ Winit,
                             const float* __restrict__ binit, unsigned short* __restrict__ Hcat,
                             float* __restrict__ c0, float* __restrict__ c1,
                             float* __restrict__ posb) {
  int idx = blockIdx.x * 256 + threadIdx.x;     // NP*512
  if (idx >= NP * 512) return;
  int n = idx >> 9, c = idx & 511;
  int blk = n / RPB_PAD, r = n - blk * RPB_PAD;
  float px = 0.f, py = 0.f;
  if (r < RPB) {
    int nr = blk * RPB + r;
    px = pos0[nr * 2 + 0];
    py = pos0[nr * 2 + 1];
  }
  float h0 = binit[c] + Winit[c * 2 + 0] * px + Winit[c * 2 + 1] * py;
  Hcat[(size_t)n * 1024 + c] = f2bf(h0);
  Hcat[(size_t)n * 1024 + 512 + c] = 0;   // h1 = 0
  c0[idx] = 0.f;
  c1[idx] = 0.f;
  if (c < 2) posb[n * 2 + c] = (c == 0) ? px : py;
}

// static_proj = Xs @ Wsp^T + b0p  (bf16, permuted cols) — SP path only
__global__ __launch_bounds__(256) void k_static(const unsigned short* __restrict__ Xs,
                                                const unsigned short* __restrict__ Wsp,
                                                const float* __restrict__ b0p,
                                                unsigned short* __restrict__ SP) {
  __shared__ __align__(16) unsigned short lds[16384];
  int tid = threadIdx.x, bn = blockIdx.x, bm = blockIdx.y;
  f32x4 acc[4][4];
  const unsigned short* Ab = Xs + (size_t)bm * 128 * 384;
  const unsigned short* Bb = Wsp + bn * 128 * 384;
  gemm_core<6, 6>(Ab, 384, Ab, 384, Bb, 384, Bb, 384, lds, acc, tid);
  int lane = tid & 63, wid = tid >> 6, wm = wid & 1, wn = wid >> 1;
  int c16 = lane & 15, q = lane >> 4;
#pragma unroll
  for (int mf = 0; mf < 4; ++mf) {
    int row0 = bm * 128 + wm * 64 + mf * 16 + q * 4;
#pragma unroll
    for (int nf = 0; nf < 4; ++nf) {
      int j = bn * 128 + wn * 64 + nf * 16 + c16;
      float bb = b0p[j];
#pragma unroll
      for (int r = 0; r < 4; ++r) SP[(size_t)(row0 + r) * 2048 + j] = f2bf(acc[mf][nf][r] + bb);
    }
  }
}

// ---------------- persistent row-owner kernel ----------------
// LDS: arena = 2 bufs x (A 384 slots + B 1024 slots) x 16B = 45,056 B; + wfc2 2KB + red 3KB.
template <bool USE_SP>
__global__ __launch_bounds__(512) void k_persist(
    unsigned short* __restrict__ Hc0, unsigned short* __restrict__ Hc1,
    float* __restrict__ c0g, float* __restrict__ c1g, float* __restrict__ posb,
    const unsigned short* __restrict__ SP, const unsigned short* __restrict__ Xs,
    const unsigned short* __restrict__ W0p, const unsigned short* __restrict__ Wc1p,
    const unsigned short* __restrict__ Wsp, const unsigned short* __restrict__ Wfc1b,
    const float* __restrict__ Wposp, const float* __restrict__ b0p,
    const float* __restrict__ b1p, const float* __restrict__ bfc1,
    const float* __restrict__ Wfc2, const float* __restrict__ bfc2,
    float* __restrict__ out) {
  __shared__ __align__(16) unsigned short arena[22528];   // elements (45,056 B)
  __shared__ float wfc2s[512];
  __shared__ float red[RPB_PAD * 8];                      // [row][wn][d]

  const int tid = threadIdx.x;
  const int blk = blockIdx.x;
  const int lane = tid & 63, w = tid >> 6, wm = w & 1, wn = w >> 1;
  const int c16 = lane & 15, q = lane >> 4;
  const size_t blkrow = (size_t)blk * RPB_PAD;

  wfc2s[tid] = Wfc2[tid];   // [2][256] row-major

  // staging slot offsets (BK=32: A 384 slots of 16B, B 1024 slots)
  const int rA = tid >> 2, cA = (tid & 3) ^ (rA & 3);
  const int oA1024 = rA * 1024 + cA * 8, oA384 = rA * 384 + cA * 8;
  const int pB1 = 512 + tid;
  const int rB0 = tid >> 2, cB0 = (tid & 3) ^ (rB0 & 3);
  const int rB1 = pB1 >> 2, cB1 = (pB1 & 3) ^ (rB1 & 3);
  const int oB512_0 = rB0 * 512 + cB0 * 8,  oB512_1 = rB1 * 512 + cB1 * 8;
  const int oB1024_0 = rB0 * 1024 + cB0 * 8, oB1024_1 = rB1 * 1024 + cB1 * 8;
  const int oB384_0 = rB0 * 384 + cB0 * 8,  oB384_1 = rB1 * 384 + cB1 * 8;

  // MFMA fragment LDS slots (per kt: k=32 -> one mfma set; chunk index = q)
  int aslot[3], bslot[4];
#pragma unroll
  for (int mf = 0; mf < 3; ++mf) {
    int row = wm * 48 + mf * 16 + c16;
    aslot[mf] = row * 4 + (q ^ (row & 3));
  }
#pragma unroll
  for (int nf = 0; nf < 4; ++nf) {
    int row = wn * 64 + nf * 16 + c16;
    bslot[nf] = row * 4 + (q ^ (row & 3));
  }

  auto stage = [&](const unsigned short* As, int oA,
                   const unsigned short* Bs, int ob0, int ob1, int bufel) {
    if (tid < 384) async_copy16(As + oA, &arena[bufel + tid * 8]);
    async_copy16(Bs + ob0, &arena[bufel + 3072 + tid * 8]);
    async_copy16(Bs + ob1, &arena[bufel + 3072 + 4096 + tid * 8]);
  };
  auto domfma = [&](int bufel, f32x4 (&acc)[3][4]) {
    bf16x8 a[3], b[4];
#pragma unroll
    for (int mf = 0; mf < 3; ++mf) a[mf] = *(const bf16x8*)&arena[bufel + aslot[mf] * 8];
#pragma unroll
    for (int nf = 0; nf < 4; ++nf) b[nf] = *(const bf16x8*)&arena[bufel + 3072 + bslot[nf] * 8];
#pragma unroll
    for (int mf = 0; mf < 3; ++mf)
#pragma unroll
      for (int nf = 0; nf < 4; ++nf)
        acc[mf][nf] = __builtin_amdgcn_mfma_f32_16x16x32_bf16(a[mf], b[nf], acc[mf][nf], 0, 0, 0);
  };

  const int KT1 = USE_SP ? 16 : 28;           // K=512 or 896, BK=32
  const unsigned short* XsB = USE_SP ? Xs : (Xs + blkrow * 384);

  for (int t = 0; t < T_STEPS; ++t) {
    unsigned short* HcurB = ((t & 1) ? Hc1 : Hc0) + blkrow * 1024;
    unsigned short* HnxtB = ((t & 1) ? Hc0 : Hc1) + blkrow * 1024;

    auto issue1 = [&](int slot, int bufel) {
      int c = slot / KT1, kt = slot - c * KT1;
      if (!USE_SP && kt >= 16) {
        int k2 = (kt - 16) * 32;
        stage(XsB + k2, oA384, Wsp + c * (256 * 384) + k2, oB384_0, oB384_1, bufel);
      } else {
        stage(HcurB + kt * 32, oA1024, W0p + c * (256 * 512) + kt * 32, oB512_0, oB512_1, bufel);
      }
    };
    auto issue2 = [&](int slot, int bufel) {
      int c = slot >> 5, kt = slot & 31;
      const unsigned short* As = (kt < 16) ? (HnxtB + kt * 32) : (HcurB + 512 + (kt - 16) * 32);
      stage(As, oA1024, Wc1p + (size_t)c * (256 * 1024) + kt * 32, oB1024_0, oB1024_1, bufel);
    };
    auto issue3 = [&](int kt, int bufel) {
      stage(HnxtB + 512 + kt * 32, oA1024, Wfc1b + kt * 32, oB512_0, oB512_1, bufel);
    };

    // ================= phase 1: gates0 + cell0 =================
    {
      issue1(0, 0);
      int cur = 0;
      const int NS = 8 * KT1;
      for (int c = 0; c < 8; ++c) {
        f32x4 acc[3][4];
#pragma unroll
        for (int i = 0; i < 3; ++i)
#pragma unroll
          for (int j = 0; j < 4; ++j) acc[i][j] = f32x4{0.f, 0.f, 0.f, 0.f};
        for (int kt = 0; kt < KT1; ++kt) {
          __syncthreads();
          int ni = c * KT1 + kt + 1;
          if (ni < NS) issue1(ni, (cur ^ 1) * 11264);
          domfma(cur * 11264, acc);
          cur ^= 1;
        }
        // epilogue chunk c (regs/global only — overlaps next chunk's in-flight loads)
        int jb = c * 256 + wn * 64 + c16;
        int cg = c * 64 + (wn >> 1) * 32 + (wn & 1) * 16 + c16;
        float wpx[4], wpy[4], sb[4];
#pragma unroll
        for (int g = 0; g < 4; ++g) {
          wpx[g] = Wposp[(jb + g * 16) * 2 + 0];
          wpy[g] = Wposp[(jb + g * 16) * 2 + 1];
          sb[g] = USE_SP ? 0.f : b0p[jb + g * 16];
        }
#pragma unroll
        for (int mf = 0; mf < 3; ++mf) {
          int rl0 = wm * 48 + mf * 16 + q * 4;
#pragma unroll
          for (int r = 0; r < 4; ++r) {
            int rl = rl0 + r;
            size_t gr = blkrow + rl;
            float px = posb[gr * 2 + 0], py = posb[gr * 2 + 1];
            float s0 = sb[0], s1 = sb[1], s2 = sb[2], s3 = sb[3];
            if (USE_SP) {
              const unsigned short* sp = SP + gr * 2048 + jb;
              s0 = bf2f(sp[0]); s1 = bf2f(sp[16]); s2 = bf2f(sp[32]); s3 = bf2f(sp[48]);
            }
            float gi = acc[mf][0][r] + s0 + px * wpx[0] + py * wpy[0];
            float gf = acc[mf][1][r] + s1 + px * wpx[1] + py * wpy[1];
            float gg = acc[mf][2][r] + s2 + px * wpx[2] + py * wpy[2];
            float go = acc[mf][3][r] + s3 + px * wpx[3] + py * wpy[3];
            float cold = c0g[gr * 512 + cg];
            float cn = fast_sigmoid(gf) * cold + fast_sigmoid(gi) * fast_tanh(gg);
            float h  = fast_sigmoid(go) * fast_tanh(cn);
            c0g[gr * 512 + cg] = cn;
            HnxtB[(size_t)rl * 1024 + cg] = f2bf(h);
          }
        }
      }
    }

    // ================= phase 2: gates1 + cell1 =================
    {
      issue2(0, 0);
      int cur = 0;
      for (int c = 0; c < 8; ++c) {
        f32x4 acc[3][4];
#pragma unroll
        for (int i = 0; i < 3; ++i)
#pragma unroll
          for (int j = 0; j < 4; ++j) acc[i][j] = f32x4{0.f, 0.f, 0.f, 0.f};
        for (int kt = 0; kt < 32; ++kt) {
          __syncthreads();
          int ni = c * 32 + kt + 1;
          if (ni < 256) issue2(ni, (cur ^ 1) * 11264);
          domfma(cur * 11264, acc);
          cur ^= 1;
        }
        int jb = c * 256 + wn * 64 + c16;
        int cg = c * 64 + (wn >> 1) * 32 + (wn & 1) * 16 + c16;
        float bi = b1p[jb], bfv = b1p[jb + 16], bg = b1p[jb + 32], bo = b1p[jb + 48];
#pragma unroll
        for (int mf = 0; mf < 3; ++mf) {
          int rl0 = wm * 48 + mf * 16 + q * 4;
#pragma unroll
          for (int r = 0; r < 4; ++r) {
            int rl = rl0 + r;
            size_t gr = blkrow + rl;
            float gi = acc[mf][0][r] + bi;
            float gf = acc[mf][1][r] + bfv;
            float gg = acc[mf][2][r] + bg;
            float go = acc[mf][3][r] + bo;
            float cold = c1g[gr * 512 + cg];
            float cn = fast_sigmoid(gf) * cold + fast_sigmoid(gi) * fast_tanh(gg);
            float h  = fast_sigmoid(go) * fast_tanh(cn);
            c1g[gr * 512 + cg] = cn;
            HnxtB[(size_t)rl * 1024 + 512 + cg] = f2bf(h);
          }
        }
      }
    }

    // ================= phase 3: fc1+relu+fc2 =================
    {
      issue3(0, 0);
      int cur = 0;
      f32x4 acc[3][4];
#pragma unroll
      for (int i = 0; i < 3; ++i)
#pragma unroll
        for (int j = 0; j < 4; ++j) acc[i][j] = f32x4{0.f, 0.f, 0.f, 0.f};
      for (int kt = 0; kt < 16; ++kt) {
        __syncthreads();
        if (kt + 1 < 16) issue3(kt + 1, (cur ^ 1) * 11264);
        domfma(cur * 11264, acc);
        cur ^= 1;
      }
      // relu + fc2 partial dots in regs, shuffle-reduce over c16
      float part[2][3][4];
#pragma unroll
      for (int d = 0; d < 2; ++d)
#pragma unroll
        for (int mf = 0; mf < 3; ++mf)
#pragma unroll
          for (int r = 0; r < 4; ++r) part[d][mf][r] = 0.f;
#pragma unroll
      for (int nf = 0; nf < 4; ++nf) {
        int col = wn * 64 + nf * 16 + c16;
        float w0 = wfc2s[col], w1 = wfc2s[256 + col], bv = bfc1[col];
#pragma unroll
        for (int mf = 0; mf < 3; ++mf)
#pragma unroll
          for (int r = 0; r < 4; ++r) {
            float v = acc[mf][nf][r] + bv;
            v = v > 0.f ? v : 0.f;
            part[0][mf][r] += v * w0;
            part[1][mf][r] += v * w1;
          }
      }
#pragma unroll
      for (int st = 1; st < 16; st <<= 1)
#pragma unroll
        for (int d = 0; d < 2; ++d)
#pragma unroll
          for (int mf = 0; mf < 3; ++mf)
#pragma unroll
            for (int r = 0; r < 4; ++r)
              part[d][mf][r] += __shfl_xor(part[d][mf][r], st, 64);
      if (c16 == 0) {
#pragma unroll
        for (int mf = 0; mf < 3; ++mf)
#pragma unroll
          for (int r = 0; r < 4; ++r) {
            int rl = wm * 48 + mf * 16 + q * 4 + r;
            red[rl * 8 + wn * 2 + 0] = part[0][mf][r];
            red[rl * 8 + wn * 2 + 1] = part[1][mf][r];
          }
      }
      __syncthreads();
      if (tid < 192) {
        int rl = tid >> 1, d = tid & 1;
        float s = bfc2[d];
#pragma unroll
        for (int j = 0; j < 4; ++j) s += red[rl * 8 + j * 2 + d];
        posb[(blkrow + rl) * 2 + d] = s;
        if (rl < RPB) out[((size_t)(blk * RPB + rl) * T_STEPS + t) * 2 + d] = s;
      }
      __syncthreads();
    }
  }
}

// ---------------- launch ----------------
extern "C" void kernel_launch(void* const* d_in, const int* in_sizes, int n_in,
                              void* d_out, int out_size, void* d_ws, size_t ws_size,
                              hipStream_t stream) {
  (void)in_sizes; (void)n_in; (void)out_size;
  const float* ctx   = (const float*)d_in[0];
  const float* pos0  = (const float*)d_in[1];
  const float* ball  = (const float*)d_in[2];
  const int*   roles = (const int*)d_in[3];
  const float* role_table = (const float*)d_in[5];
  const float* Wih0 = (const float*)d_in[6];
  const float* Whh0 = (const float*)d_in[7];
  const float* b0   = (const float*)d_in[8];
  const float* Wih1 = (const float*)d_in[9];
  const float* Whh1 = (const float*)d_in[10];
  const float* b1   = (const float*)d_in[11];
  const float* Wfc1 = (const float*)d_in[12];
  const float* bfc1 = (const float*)d_in[13];
  const float* Wfc2 = (const float*)d_in[14];
  const float* bfc2 = (const float*)d_in[15];
  const float* Winit = (const float*)d_in[16];
  const float* binit = (const float*)d_in[17];
  float* out = (float*)d_out;

  char* w = (char*)d_ws;
  size_t used = 0;
  auto alloc = [&](size_t bytes) {
    char* p = w + used;
    used += (bytes + 255) & ~(size_t)255;
    return p;
  };
  unsigned short* W0p   = (unsigned short*)alloc((size_t)2048 * 512 * 2);
  unsigned short* Wc1p  = (unsigned short*)alloc((size_t)2048 * 1024 * 2);
  unsigned short* Wfc1b = (unsigned short*)alloc((size_t)256 * 512 * 2);
  float* Wposp = (float*)alloc(2048 * 8);
  float* b0p   = (float*)alloc(2048 * 4);
  float* b1p   = (float*)alloc(2048 * 4);
  float* posb  = (float*)alloc((size_t)NP * 2 * 4);
  unsigned short* Hc0 = (unsigned short*)alloc((size_t)NP * 1024 * 2);
  float* c0   = (float*)alloc((size_t)NP * 512 * 4);
  float* c1   = (float*)alloc((size_t)NP * 512 * 4);
  unsigned short* Hc1 = (unsigned short*)alloc((size_t)NP * 1024 * 2);

  const size_t SP_BYTES = (size_t)NP * 2048 * 2;            // 96 MB
  const bool use_sp = (ws_size >= used + SP_BYTES + (1u << 20));

  unsigned short *Xs, *Wsp, *SP;
  if (use_sp) {
    SP  = (unsigned short*)alloc(SP_BYTES);
    Xs  = Hc1;                                 // transient: dead before Hc1 is written
    Wsp = Hc1 + (size_t)NP * 384;
  } else {
    SP  = Hc1;                                 // never dereferenced on lite path
    Xs  = (unsigned short*)alloc((size_t)NP * 384 * 2);
    Wsp = (unsigned short*)alloc((size_t)2048 * 384 * 2);
  }

  k_prep_w<<<2048, 512, 0, stream>>>(Whh0, Wih1, Whh1, Wih0, Wfc1, b0, b1,
                                     W0p, Wc1p, Wsp, Wfc1b, Wposp, b0p, b1p);
  k_init_xs<<<NP, 384, 0, stream>>>(ball, ctx, roles, role_table, Xs);
  k_init_state<<<(NP * 512 + 255) / 256, 256, 0, stream>>>(pos0, Winit, binit, Hc0, c0, c1, posb);

  if (use_sp) {
    dim3 gs(16, NP / 128);
    k_static<<<gs, 256, 0, stream>>>(Xs, Wsp, b0p, SP);
    k_persist<true><<<NBLK, 512, 0, stream>>>(Hc0, Hc1, c0, c1, posb, SP, Xs,
                                              W0p, Wc1p, Wsp, Wfc1b, Wposp, b0p, b1p,
                                              bfc1, Wfc2, bfc2, out);
  } else {
    k_persist<false><<<NBLK, 512, 0, stream>>>(Hc0, Hc1, c0, c1, posb, SP, Xs,
                                               W0p, Wc1p, Wsp, Wfc1b, Wposp, b0p, b1p,
                                               bfc1, Wfc2, bfc2, out);
  }
}

// Round 4
// 27220.770 us; speedup vs baseline: 1.6578x; 1.6578x over previous
//
#include <hip/hip_runtime.h>
#include <cstdint>

// RoleConditionedLSTMDecoder on MI355X (gfx950) — R4: refined R2 multi-kernel.
// B=1024 P=22 N=22528 H=512 4H=2048 T=100.
//  - Gate-permuted weight rows: perm j = tile*128 + half*64 + gate*16 + c16
//    (h-col = tile*32 + half*16 + c16) -> lane's 4 col-frags hold i,f,g,o of one
//    (row, h-col): LSTM cell update is per-lane epilogue math.
//  - bf16 MFMA 16x16x32, fp32 accum + cell state; ping-pong Hcat[N,1024]=[h0|h1].
//  - SP stored PACKED: ushort4 {i,f,g,o} per (row, h-col) -> 1 coalesced 8B load
//    per output in S1 epilogue (was 4 scalar 2B loads). Wpos/b0/b1 packed float4/h-col.
//  - S3 fc2 via in-register relu+partial-dot + shfl_xor reduce (no bf16 roundtrip).

#define DEVI __device__ __forceinline__

typedef __bf16 bf16x8 __attribute__((ext_vector_type(8)));
typedef float  f32x4  __attribute__((ext_vector_type(4)));
typedef float  f32x2  __attribute__((ext_vector_type(2)));
typedef unsigned short u16x4 __attribute__((ext_vector_type(4)));

static constexpr int NROWS = 22528;   // B*P
static constexpr int T_STEPS = 100;

DEVI unsigned short f2bf(float f) {
  unsigned u = __float_as_uint(f);
  u = u + 0x7FFFu + ((u >> 16) & 1u);   // RNE
  return (unsigned short)(u >> 16);
}
DEVI float bf2f(unsigned short h) { return __uint_as_float(((unsigned)h) << 16); }

DEVI float fast_sigmoid(float x) {
  float e = __builtin_amdgcn_exp2f(-1.442695041f * x);
  return __builtin_amdgcn_rcpf(1.0f + e);
}
DEVI float fast_tanh(float x) {
  float e = __builtin_amdgcn_exp2f(2.885390082f * x);   // e^(2x)
  return 1.0f - 2.0f * __builtin_amdgcn_rcpf(e + 1.0f);
}

DEVI void async_copy16(const void* g, void* l) {
  __builtin_amdgcn_global_load_lds(
      (const __attribute__((address_space(1))) void*)g,
      (__attribute__((address_space(3))) void*)l, 16, 0, 0);
}

// ---------------- 128x128 GEMM core (BK=64, 256 thr, 4 waves 2x2) — proven R2 ----------------
// A and B may each split at k = KSWITCH*64. LDS tile: [row][8 chunks of 16B],
// chunk XOR-swizzled by (row&7) on the SOURCE side -> 2-way read aliasing only (free).
template <int KITERS, int KSWITCH>
DEVI void gemm_core(const unsigned short* __restrict__ A1, int lda1,
                    const unsigned short* __restrict__ A2, int lda2,
                    const unsigned short* __restrict__ B1, int ldb1,
                    const unsigned short* __restrict__ B2, int ldb2,
                    unsigned short* lds, f32x4 acc[4][4], int tid) {
  const int lane = tid & 63, wid = tid >> 6;
  const int wm = wid & 1, wn = wid >> 1;
  const int c16 = lane & 15, q = lane >> 4;
#pragma unroll
  for (int i = 0; i < 4; ++i)
#pragma unroll
    for (int j = 0; j < 4; ++j) acc[i][j] = f32x4{0.f, 0.f, 0.f, 0.f};
  for (int kt = 0; kt < KITERS; ++kt) {
    const bool sec = (kt >= KSWITCH);
    const unsigned short* Ab = sec ? A2 : A1;
    const unsigned short* Bb = sec ? B2 : B1;
    const int lda = sec ? lda2 : lda1;
    const int ldb = sec ? ldb2 : ldb1;
    const int kk = (sec ? (kt - KSWITCH) : kt) * 64;
    __syncthreads();                       // prior reads done before overwrite
#pragma unroll
    for (int rd = 0; rd < 4; ++rd) {
      int p = rd * 256 + tid;
      int row = p >> 3, u = p & 7, ch = u ^ (row & 7);
      async_copy16(Ab + row * lda + kk + ch * 8, lds + p * 8);
      async_copy16(Bb + row * ldb + kk + ch * 8, lds + 8192 + p * 8);
    }
    __syncthreads();                       // compiler drains vmcnt before barrier
#pragma unroll
    for (int s = 0; s < 2; ++s) {
      bf16x8 a[4], b[4];
#pragma unroll
      for (int mf = 0; mf < 4; ++mf) {
        int row = wm * 64 + mf * 16 + c16;
        int slot = row * 8 + ((s * 4 + q) ^ (row & 7));
        a[mf] = *(const bf16x8*)(lds + slot * 8);
      }
#pragma unroll
      for (int nf = 0; nf < 4; ++nf) {
        int row = wn * 64 + nf * 16 + c16;
        int slot = row * 8 + ((s * 4 + q) ^ (row & 7));
        b[nf] = *(const bf16x8*)(lds + 8192 + slot * 8);
      }
#pragma unroll
      for (int mf = 0; mf < 4; ++mf)
#pragma unroll
        for (int nf = 0; nf < 4; ++nf)
          acc[mf][nf] = __builtin_amdgcn_mfma_f32_16x16x32_bf16(a[mf], b[nf], acc[mf][nf], 0, 0, 0);
    }
  }
}

// ---------------- prep ----------------
DEVI int orig_row(int j) {  // permuted gate-col -> original row of [4H x K] weight
  int tile = j >> 7, rem = j & 127;
  int half = rem >> 6, g = (rem >> 4) & 3, cc = rem & 15;
  return g * 512 + (tile * 32 + half * 16 + cc);
}

__global__ void k_prep_w(const float* __restrict__ Whh0, const float* __restrict__ Wih1,
                         const float* __restrict__ Whh1, const float* __restrict__ Wih0,
                         const float* __restrict__ Wfc1, const float* __restrict__ b0,
                         const float* __restrict__ b1,
                         unsigned short* __restrict__ W0p, unsigned short* __restrict__ Wc1p,
                         unsigned short* __restrict__ Wsp, unsigned short* __restrict__ Wfc1b,
                         float* __restrict__ Wposx, float* __restrict__ Wposy,
                         float* __restrict__ b0p4, float* __restrict__ b1p4) {
  int j = blockIdx.x;       // 0..2047
  int k = threadIdx.x;      // 0..511
  int o = orig_row(j);
  W0p[j * 512 + k]         = f2bf(Whh0[o * 512 + k]);
  Wc1p[j * 1024 + k]       = f2bf(Wih1[o * 512 + k]);
  Wc1p[j * 1024 + 512 + k] = f2bf(Whh1[o * 512 + k]);
  if (k < 384) Wsp[j * 384 + k] = (k < 322) ? f2bf(Wih0[o * 324 + 2 + k]) : (unsigned short)0;
  if (k == 0) {
    int g = (j >> 4) & 3;
    int cg = (j >> 7) * 32 + ((j >> 6) & 1) * 16 + (j & 15);
    Wposx[cg * 4 + g] = Wih0[o * 324 + 0];
    Wposy[cg * 4 + g] = Wih0[o * 324 + 1];
    b0p4[cg * 4 + g] = b0[o];
    b1p4[cg * 4 + g] = b1[o];
  }
  if (j < 256) Wfc1b[j * 512 + k] = f2bf(Wfc1[j * 512 + k]);
}

__global__ void k_init_xs(const float* __restrict__ ball, const float* __restrict__ ctx,
                          const int* __restrict__ roles, const float* __restrict__ role_table,
                          unsigned short* __restrict__ Xs) {
  int n = blockIdx.x, col = threadIdx.x;  // 22528 x 384
  int b = n / 22;
  float v;
  if (col < 2)        v = ball[b * 2 + col];
  else if (col < 258) v = ctx[(size_t)n * 256 + col - 2];
  else if (col < 322) v = role_table[roles[n] * 64 + col - 258];
  else                v = 0.f;
  Xs[(size_t)n * 384 + col] = f2bf(v);
}

__global__ void k_init_state(const float* __restrict__ pos0, const float* __restrict__ Winit,
                             const float* __restrict__ binit, unsigned short* __restrict__ Hcat,
                             float* __restrict__ c0, float* __restrict__ c1,
                             float* __restrict__ posb) {
  int idx = blockIdx.x * 256 + threadIdx.x;     // N*512
  if (idx >= NROWS * 512) return;
  int n = idx >> 9, c = idx & 511;
  float px = pos0[n * 2 + 0], py = pos0[n * 2 + 1];
  float h0 = binit[c] + Winit[c * 2 + 0] * px + Winit[c * 2 + 1] * py;
  Hcat[(size_t)n * 1024 + c] = f2bf(h0);
  Hcat[(size_t)n * 1024 + 512 + c] = 0;   // h1 = 0
  c0[idx] = 0.f;
  c1[idx] = 0.f;
  if (c < 2) posb[n * 2 + c] = pos0[n * 2 + c];
}

// static_proj packed: SP2[(row*512+cg)] = ushort4{i,f,g,o} + b0 — SP path only
__global__ __launch_bounds__(256) void k_static(const unsigned short* __restrict__ Xs,
                                                const unsigned short* __restrict__ Wsp,
                                                const float* __restrict__ b0p4,
                                                unsigned short* __restrict__ SP2) {
  __shared__ __align__(16) unsigned short lds[16384];
  int tid = threadIdx.x, bn = blockIdx.x, bm = blockIdx.y;
  f32x4 acc[4][4];
  const unsigned short* Ab = Xs + (size_t)bm * 128 * 384;
  const unsigned short* Bb = Wsp + (size_t)bn * 128 * 384;
  gemm_core<6, 6>(Ab, 384, Ab, 384, Bb, 384, Bb, 384, lds, acc, tid);
  int lane = tid & 63, wid = tid >> 6, wm = wid & 1, wn = wid >> 1;
  int c16 = lane & 15, q = lane >> 4;
  int cg = bn * 32 + wn * 16 + c16;                 // h-col; gate index = nf
  f32x4 bb = *(const f32x4*)&b0p4[cg * 4];
#pragma unroll
  for (int mf = 0; mf < 4; ++mf) {
    int row0 = bm * 128 + wm * 64 + mf * 16 + q * 4;
#pragma unroll
    for (int r = 0; r < 4; ++r) {
      u16x4 v;
      v.x = f2bf(acc[mf][0][r] + bb.x);
      v.y = f2bf(acc[mf][1][r] + bb.y);
      v.z = f2bf(acc[mf][2][r] + bb.z);
      v.w = f2bf(acc[mf][3][r] + bb.w);
      ((u16x4*)SP2)[(size_t)(row0 + r) * 512 + cg] = v;
    }
  }
}

// ---------------- per-step ----------------
// S1: gates0 = h0_prev @ W0p^T (+ static) + pos@Wpos^T ; cell0 -> h0 into nxt[:,0:512]
template <bool USE_SP>
__global__ __launch_bounds__(256) void k_s1(const unsigned short* __restrict__ cur,
                                            const unsigned short* __restrict__ Xs,
                                            const unsigned short* __restrict__ W0p,
                                            const unsigned short* __restrict__ Wsp,
                                            const unsigned short* __restrict__ SP2,
                                            const float* __restrict__ b0p4,
                                            const float* __restrict__ Wposx,
                                            const float* __restrict__ Wposy,
                                            const float* __restrict__ posb,
                                            float* __restrict__ c0,
                                            unsigned short* __restrict__ nxt) {
  __shared__ __align__(16) unsigned short lds[16384];
  int tid = threadIdx.x, bn = blockIdx.x, bm = blockIdx.y;
  f32x4 acc[4][4];
  const unsigned short* A1 = cur + (size_t)bm * 128 * 1024;
  const unsigned short* B1 = W0p + (size_t)bn * 128 * 512;
  if constexpr (USE_SP) {
    gemm_core<8, 8>(A1, 1024, A1, 1024, B1, 512, B1, 512, lds, acc, tid);
  } else {
    const unsigned short* A2 = Xs + (size_t)bm * 128 * 384;
    const unsigned short* B2 = Wsp + (size_t)bn * 128 * 384;
    gemm_core<14, 8>(A1, 1024, A2, 384, B1, 512, B2, 384, lds, acc, tid);
  }
  int lane = tid & 63, wid = tid >> 6, wm = wid & 1, wn = wid >> 1;
  int c16 = lane & 15, q = lane >> 4;
  int cg = bn * 32 + wn * 16 + c16;          // global h-col
  f32x4 wpx = *(const f32x4*)&Wposx[cg * 4];
  f32x4 wpy = *(const f32x4*)&Wposy[cg * 4];
  f32x4 sb = f32x4{0.f, 0.f, 0.f, 0.f};
  if constexpr (!USE_SP) sb = *(const f32x4*)&b0p4[cg * 4];
#pragma unroll
  for (int mf = 0; mf < 4; ++mf) {
    int row0 = bm * 128 + wm * 64 + mf * 16 + q * 4;
#pragma unroll
    for (int r = 0; r < 4; ++r) {
      size_t row = row0 + r;
      f32x2 pv = *(const f32x2*)&posb[row * 2];
      float s0 = sb.x, s1 = sb.y, s2 = sb.z, s3 = sb.w;
      if constexpr (USE_SP) {
        u16x4 sp = ((const u16x4*)SP2)[row * 512 + cg];
        s0 = bf2f(sp.x); s1 = bf2f(sp.y); s2 = bf2f(sp.z); s3 = bf2f(sp.w);
      }
      float gi = acc[mf][0][r] + s0 + pv.x * wpx.x + pv.y * wpy.x;
      float gf = acc[mf][1][r] + s1 + pv.x * wpx.y + pv.y * wpy.y;
      float gg = acc[mf][2][r] + s2 + pv.x * wpx.z + pv.y * wpy.z;
      float go = acc[mf][3][r] + s3 + pv.x * wpx.w + pv.y * wpy.w;
      float cold = c0[row * 512 + cg];
      float cn = fast_sigmoid(gf) * cold + fast_sigmoid(gi) * fast_tanh(gg);
      float h  = fast_sigmoid(go) * fast_tanh(cn);
      c0[row * 512 + cg] = cn;
      nxt[row * 1024 + cg] = f2bf(h);
    }
  }
}

// S2: gates1 = [h0_t | h1_prev] @ Wc1p^T + b1 ; cell1 -> h1 into nxt[:,512:]
__global__ __launch_bounds__(256) void k_s2(const unsigned short* __restrict__ nxt_in,
                                            const unsigned short* __restrict__ cur,
                                            const unsigned short* __restrict__ Wc1p,
                                            const float* __restrict__ b1p4,
                                            float* __restrict__ c1,
                                            unsigned short* __restrict__ nxt_out) {
  __shared__ __align__(16) unsigned short lds[16384];
  int tid = threadIdx.x, bn = blockIdx.x, bm = blockIdx.y;
  f32x4 acc[4][4];
  const unsigned short* A1 = nxt_in + (size_t)bm * 128 * 1024;        // h0_t (cols 0..511)
  const unsigned short* A2 = cur + (size_t)bm * 128 * 1024 + 512;     // h1_{t-1}
  const unsigned short* B1 = Wc1p + (size_t)bn * 128 * 1024;
  gemm_core<16, 8>(A1, 1024, A2, 1024, B1, 1024, B1 + 512, 1024, lds, acc, tid);
  int lane = tid & 63, wid = tid >> 6, wm = wid & 1, wn = wid >> 1;
  int c16 = lane & 15, q = lane >> 4;
  int cg = bn * 32 + wn * 16 + c16;
  f32x4 bv = *(const f32x4*)&b1p4[cg * 4];
#pragma unroll
  for (int mf = 0; mf < 4; ++mf) {
    int row0 = bm * 128 + wm * 64 + mf * 16 + q * 4;
#pragma unroll
    for (int r = 0; r < 4; ++r) {
      size_t row = row0 + r;
      float gi = acc[mf][0][r] + bv.x;
      float gf = acc[mf][1][r] + bv.y;
      float gg = acc[mf][2][r] + bv.z;
      float go = acc[mf][3][r] + bv.w;
      float cold = c1[row * 512 + cg];
      float cn = fast_sigmoid(gf) * cold + fast_sigmoid(gi) * fast_tanh(gg);
      float h  = fast_sigmoid(go) * fast_tanh(cn);
      c1[row * 512 + cg] = cn;
      nxt_out[row * 1024 + 512 + cg] = f2bf(h);
    }
  }
}

// S3: pos = relu(h1 @ Wfc1^T + bfc1) @ Wfc2^T + bfc2 ; write preds[:,t], posb.
// 64 rows x 256 cols/block; fc2 via in-register partial dots + shfl_xor reduce.
__global__ __launch_bounds__(256) void k_s3(const unsigned short* __restrict__ H,
                                            const unsigned short* __restrict__ Wfc1b,
                                            const float* __restrict__ bfc1,
                                            const float* __restrict__ Wfc2,
                                            const float* __restrict__ bfc2,
                                            float* __restrict__ out, float* __restrict__ posb,
                                            int t) {
  __shared__ __align__(16) unsigned short ldsA[64 * 64];    // 8 KB
  __shared__ __align__(16) unsigned short ldsB[256 * 64];   // 32 KB
  __shared__ float wfc2s[512];                              // 2 KB
  __shared__ float red[64 * 4];                             // [row][wn*2+d], 1 KB
  int tid = threadIdx.x, bm = blockIdx.x;
  wfc2s[tid] = Wfc2[tid];
  wfc2s[tid + 256] = Wfc2[tid + 256];
  int lane = tid & 63, wid = tid >> 6, wm = wid & 1, wn = wid >> 1;
  int c16 = lane & 15, q = lane >> 4;
  f32x4 acc[2][8];
#pragma unroll
  for (int i = 0; i < 2; ++i)
#pragma unroll
    for (int j = 0; j < 8; ++j) acc[i][j] = f32x4{0.f, 0.f, 0.f, 0.f};
  const unsigned short* Ab = H + (size_t)bm * 64 * 1024 + 512;
  for (int kt = 0; kt < 8; ++kt) {
    int k0 = kt * 64;
    __syncthreads();
#pragma unroll
    for (int rd = 0; rd < 2; ++rd) {
      int p = rd * 256 + tid;
      int row = p >> 3, u = p & 7, ch = u ^ (row & 7);
      async_copy16(Ab + row * 1024 + k0 + ch * 8, ldsA + p * 8);
    }
#pragma unroll
    for (int rd = 0; rd < 8; ++rd) {
      int p = rd * 256 + tid;
      int row = p >> 3, u = p & 7, ch = u ^ (row & 7);
      async_copy16(Wfc1b + row * 512 + k0 + ch * 8, ldsB + p * 8);
    }
    __syncthreads();
#pragma unroll
    for (int s = 0; s < 2; ++s) {
      bf16x8 a[2], b[8];
#pragma unroll
      for (int mf = 0; mf < 2; ++mf) {
        int row = wm * 32 + mf * 16 + c16;
        int slot = row * 8 + ((s * 4 + q) ^ (row & 7));
        a[mf] = *(const bf16x8*)(ldsA + slot * 8);
      }
#pragma unroll
      for (int nf = 0; nf < 8; ++nf) {
        int row = wn * 128 + nf * 16 + c16;
        int slot = row * 8 + ((s * 4 + q) ^ (row & 7));
        b[nf] = *(const bf16x8*)(ldsB + slot * 8);
      }
#pragma unroll
      for (int mf = 0; mf < 2; ++mf)
#pragma unroll
        for (int nf = 0; nf < 8; ++nf)
          acc[mf][nf] = __builtin_amdgcn_mfma_f32_16x16x32_bf16(a[mf], b[nf], acc[mf][nf], 0, 0, 0);
    }
  }
  // relu + fc2 partial dots (fp32, no bf16 roundtrip), reduce over cols
  float part[2][2][4];   // [d][mf][r]
#pragma unroll
  for (int d = 0; d < 2; ++d)
#pragma unroll
    for (int mf = 0; mf < 2; ++mf)
#pragma unroll
      for (int r = 0; r < 4; ++r) part[d][mf][r] = 0.f;
#pragma unroll
  for (int nf = 0; nf < 8; ++nf) {
    int col = wn * 128 + nf * 16 + c16;
    float w0 = wfc2s[col], w1 = wfc2s[256 + col], bv = bfc1[col];
#pragma unroll
    for (int mf = 0; mf < 2; ++mf)
#pragma unroll
      for (int r = 0; r < 4; ++r) {
        float v = acc[mf][nf][r] + bv;
        v = v > 0.f ? v : 0.f;
        part[0][mf][r] += v * w0;
        part[1][mf][r] += v * w1;
      }
  }
#pragma unroll
  for (int st = 1; st < 16; st <<= 1)
#pragma unroll
    for (int d = 0; d < 2; ++d)
#pragma unroll
      for (int mf = 0; mf < 2; ++mf)
#pragma unroll
        for (int r = 0; r < 4; ++r)
          part[d][mf][r] += __shfl_xor(part[d][mf][r], st, 64);
  if (c16 == 0) {
#pragma unroll
    for (int mf = 0; mf < 2; ++mf)
#pragma unroll
      for (int r = 0; r < 4; ++r) {
        int rl = wm * 32 + mf * 16 + q * 4 + r;
        red[rl * 4 + wn * 2 + 0] = part[0][mf][r];
        red[rl * 4 + wn * 2 + 1] = part[1][mf][r];
      }
  }
  __syncthreads();
  if (tid < 128) {
    int rl = tid >> 1, d = tid & 1;
    float s = red[rl * 4 + d] + red[rl * 4 + 2 + d] + bfc2[d];
    int rg = bm * 64 + rl;
    out[((size_t)rg * T_STEPS + t) * 2 + d] = s;
    posb[rg * 2 + d] = s;
  }
}

// ---------------- launch ----------------
extern "C" void kernel_launch(void* const* d_in, const int* in_sizes, int n_in,
                              void* d_out, int out_size, void* d_ws, size_t ws_size,
                              hipStream_t stream) {
  (void)in_sizes; (void)n_in; (void)out_size;
  const float* ctx   = (const float*)d_in[0];
  const float* pos0  = (const float*)d_in[1];
  const float* ball  = (const float*)d_in[2];
  const int*   roles = (const int*)d_in[3];
  const float* role_table = (const float*)d_in[5];
  const float* Wih0 = (const float*)d_in[6];
  const float* Whh0 = (const float*)d_in[7];
  const float* b0   = (const float*)d_in[8];
  const float* Wih1 = (const float*)d_in[9];
  const float* Whh1 = (const float*)d_in[10];
  const float* b1   = (const float*)d_in[11];
  const float* Wfc1 = (const float*)d_in[12];
  const float* bfc1 = (const float*)d_in[13];
  const float* Wfc2 = (const float*)d_in[14];
  const float* bfc2 = (const float*)d_in[15];
  const float* Winit = (const float*)d_in[16];
  const float* binit = (const float*)d_in[17];
  float* out = (float*)d_out;

  char* w = (char*)d_ws;
  size_t used = 0;
  auto alloc = [&](size_t bytes) {
    char* p = w + used;
    used += (bytes + 255) & ~(size_t)255;
    return p;
  };
  unsigned short* W0p   = (unsigned short*)alloc((size_t)2048 * 512 * 2);
  unsigned short* Wc1p  = (unsigned short*)alloc((size_t)2048 * 1024 * 2);
  unsigned short* Wfc1b = (unsigned short*)alloc((size_t)256 * 512 * 2);
  float* Wposx = (float*)alloc(2048 * 4);
  float* Wposy = (float*)alloc(2048 * 4);
  float* b0p4  = (float*)alloc(2048 * 4);
  float* b1p4  = (float*)alloc(2048 * 4);
  float* posb  = (float*)alloc((size_t)NROWS * 2 * 4);
  unsigned short* Hc0 = (unsigned short*)alloc((size_t)NROWS * 1024 * 2);
  float* c0   = (float*)alloc((size_t)NROWS * 512 * 4);
  float* c1   = (float*)alloc((size_t)NROWS * 512 * 4);
  unsigned short* Hc1 = (unsigned short*)alloc((size_t)NROWS * 1024 * 2);

  const size_t SP_BYTES = (size_t)NROWS * 2048 * 2;           // 92.3 MB
  const bool use_sp = (ws_size >= used + SP_BYTES + (1u << 20));

  unsigned short *Xs, *Wsp, *SP2;
  if (use_sp) {
    SP2 = (unsigned short*)alloc(SP_BYTES);
    Xs  = Hc1;                                 // transient: dead before Hc1 is written
    Wsp = Hc1 + (size_t)NROWS * 384;
  } else {
    SP2 = Hc1;                                 // never dereferenced on lite path
    Xs  = (unsigned short*)alloc((size_t)NROWS * 384 * 2);
    Wsp = (unsigned short*)alloc((size_t)2048 * 384 * 2);
  }

  k_prep_w<<<2048, 512, 0, stream>>>(Whh0, Wih1, Whh1, Wih0, Wfc1, b0, b1,
                                     W0p, Wc1p, Wsp, Wfc1b, Wposx, Wposy, b0p4, b1p4);
  k_init_xs<<<NROWS, 384, 0, stream>>>(ball, ctx, roles, role_table, Xs);
  k_init_state<<<(NROWS * 512 + 255) / 256, 256, 0, stream>>>(pos0, Winit, binit, Hc0, c0, c1, posb);

  dim3 g1(16, 176);
  if (use_sp) k_static<<<g1, 256, 0, stream>>>(Xs, Wsp, b0p4, SP2);

  for (int t = 0; t < T_STEPS; ++t) {
    unsigned short* cur = (t & 1) ? Hc1 : Hc0;
    unsigned short* nxt = (t & 1) ? Hc0 : Hc1;
    if (use_sp)
      k_s1<true><<<g1, 256, 0, stream>>>(cur, Xs, W0p, Wsp, SP2, b0p4, Wposx, Wposy, posb, c0, nxt);
    else
      k_s1<false><<<g1, 256, 0, stream>>>(cur, Xs, W0p, Wsp, SP2, b0p4, Wposx, Wposy, posb, c0, nxt);
    k_s2<<<g1, 256, 0, stream>>>(nxt, cur, Wc1p, b1p4, c1, nxt);
    k_s3<<<352, 256, 0, stream>>>(nxt, Wfc1b, bfc1, Wfc2, bfc2, out, posb, t);
  }
}